// Round 3
// baseline (369.736 us; speedup 1.0000x reference)
//
#include <hip/hip_runtime.h>
#include <math.h>

#define Bsz  64
#define Cch  2048
#define Kdim 768
#define Ssp  361

// ---------------------------------------------------------------------------
// K1: qT[c][b] = dot(text[b,:], W[c,:]) + bias[c]
// grid = (256, 8) x 256 threads; wave owns 2 channels (W rows in 24 VGPRs),
// block-row y handles 8 of the 64 batches -> 32 waves/CU hide the
// text-load + shuffle-reduce latency chain. W re-read x8 (50 MB, L2/L3-hot).
// ---------------------------------------------------------------------------
__global__ __launch_bounds__(256) void k_qgemm(
    const float* __restrict__ text, const float* __restrict__ W,
    const float* __restrict__ bias, float* __restrict__ qT)
{
    const int lane = threadIdx.x & 63;
    const int wv   = threadIdx.x >> 6;
    const int c0   = blockIdx.x * 8 + wv * 2;   // this wave's first channel
    const int b0   = blockIdx.y * 8;            // this block-row's batches

    const float4* wA = (const float4*)(W + (size_t)c0 * Kdim);
    const float4* wB = (const float4*)(W + (size_t)(c0 + 1) * Kdim);
    const float4 a0 = wA[lane*3+0], a1 = wA[lane*3+1], a2 = wA[lane*3+2];
    const float4 b0v = wB[lane*3+0], b1v = wB[lane*3+1], b2v = wB[lane*3+2];
    const float biasA = bias[c0], biasB = bias[c0 + 1];

    for (int b = b0; b < b0 + 8; b++) {
        const float4* t = (const float4*)(text + (size_t)b * Kdim);
        const float4 t0 = t[lane*3+0], t1 = t[lane*3+1], t2 = t[lane*3+2];
        float r0 = a0.x*t0.x + a0.y*t0.y + a0.z*t0.z + a0.w*t0.w
                 + a1.x*t1.x + a1.y*t1.y + a1.z*t1.z + a1.w*t1.w
                 + a2.x*t2.x + a2.y*t2.y + a2.z*t2.z + a2.w*t2.w;
        float r1 = b0v.x*t0.x + b0v.y*t0.y + b0v.z*t0.z + b0v.w*t0.w
                 + b1v.x*t1.x + b1v.y*t1.y + b1v.z*t1.z + b1v.w*t1.w
                 + b2v.x*t2.x + b2v.y*t2.y + b2v.z*t2.z + b2v.w*t2.w;
        #pragma unroll
        for (int off = 32; off; off >>= 1) {
            r0 += __shfl_xor(r0, off);
            r1 += __shfl_xor(r1, off);
        }
        if (lane == 0) {
            qT[(size_t)c0 * Bsz + b]       = r0 + biasA;
            qT[(size_t)(c0 + 1) * Bsz + b] = r1 + biasB;
        }
    }
}

// ---------------------------------------------------------------------------
// K2: partial sims + fused softmax (last-block-per-batch pattern).
// grid (b=64, cg=16) x 384 threads; thread = spatial s.
// sims_part[b][cg][s] = sum over 128 channels of q[b,c]*img[b,c,s].
// The last block to finish for batch b (device-scope atomic counter,
// __threadfence release/acquire per cross-XCD rules) sums the 16 partials,
// does the softmax, and writes PRE-NORMALIZED weights wts[b][s].
// This is the HBM-streaming pass (189 MB) — at the BW ceiling.
// ---------------------------------------------------------------------------
__global__ __launch_bounds__(384) void k_sims(
    const float* __restrict__ img, const float* __restrict__ qT,
    float* __restrict__ sims_part, float* __restrict__ wts,
    int* __restrict__ cnt)
{
    const int b  = blockIdx.x;
    const int cg = blockIdx.y;
    const int tid = threadIdx.x;

    __shared__ float qL[128];
    if (tid < 128) qL[tid] = qT[(size_t)(cg * 128 + tid) * Bsz + b];
    __syncthreads();

    if (tid < Ssp) {
        const float* base = img + ((size_t)b * Cch + (size_t)cg * 128) * Ssp + tid;
        float acc = 0.f;
        #pragma unroll 8
        for (int c = 0; c < 128; c++)
            acc += qL[c] * base[(size_t)c * Ssp];
        sims_part[((size_t)b * 16 + cg) * Ssp + tid] = acc;
    }

    // --- last-block election for batch b ---
    __syncthreads();
    __shared__ int isLast;
    if (tid == 0) {
        __threadfence();                      // release our partial writes
        isLast = (atomicAdd(&cnt[b], 1) == 15);
    }
    __syncthreads();
    if (!isLast) return;
    __threadfence();                          // acquire others' partial writes

    // --- softmax over s for batch b (384 threads, 6 waves) ---
    const int lane = tid & 63;
    const int wv   = tid >> 6;
    __shared__ float red[6];

    float s0 = -1e30f;
    if (tid < Ssp) {
        float a = 0.f;
        #pragma unroll
        for (int g = 0; g < 16; g++)
            a += sims_part[((size_t)b * 16 + g) * Ssp + tid];
        s0 = a;
    }

    float m = s0;
    #pragma unroll
    for (int off = 32; off; off >>= 1) m = fmaxf(m, __shfl_xor(m, off));
    if (lane == 0) red[wv] = m;
    __syncthreads();
    m = red[0];
    #pragma unroll
    for (int w = 1; w < 6; w++) m = fmaxf(m, red[w]);
    __syncthreads();   // everyone done reading red before reuse

    const float e0 = (tid < Ssp) ? __expf(s0 - m) : 0.f;
    float l = e0;
    #pragma unroll
    for (int off = 32; off; off >>= 1) l += __shfl_xor(l, off);
    if (lane == 0) red[wv] = l;
    __syncthreads();
    l = red[0] + red[1] + red[2] + red[3] + red[4] + red[5];

    if (tid < Ssp)
        wts[(size_t)b * Ssp + tid] = e0 / l;
}

// ---------------------------------------------------------------------------
// K3: weighted pooling. grid (b=64, cg=16) x 512 threads; each wave owns 16
// channels, processed 2-at-a-time for load ILP (12 outstanding vs 6).
// Coalesced img reads (second pass — L3-resident), shuffle reduce,
// coalesced 128-wide store via LDS gather. Weights pre-normalized.
// ---------------------------------------------------------------------------
__global__ __launch_bounds__(512) void k_pool(
    const float* __restrict__ img, const float* __restrict__ wts,
    float* __restrict__ out)
{
    const int b   = blockIdx.x;
    const int cg  = blockIdx.y;
    const int tid = threadIdx.x;
    const int lane = tid & 63;
    const int wv   = tid >> 6;

    __shared__ float w[Ssp];
    __shared__ float outL[128];

    if (tid < Ssp) w[tid] = wts[(size_t)b * Ssp + tid];
    __syncthreads();

    // wave wv handles channels [cg*128 + wv*16, +16), two at a time
    const int cbase = cg * 128 + wv * 16;
    #pragma unroll 2
    for (int cc = 0; cc < 16; cc += 2) {
        const float* base0 = img + ((size_t)b * Cch + cbase + cc) * Ssp;
        const float* base1 = base0 + Ssp;
        float p0 = 0.f, p1 = 0.f;
        #pragma unroll
        for (int j = 0; j < 5; j++) {
            const float wj = w[lane + 64 * j];
            p0 += base0[lane + 64 * j] * wj;
            p1 += base1[lane + 64 * j] * wj;
        }
        if (lane + 320 < Ssp) {
            const float wt = w[lane + 320];
            p0 += base0[lane + 320] * wt;
            p1 += base1[lane + 320] * wt;
        }
        #pragma unroll
        for (int off = 32; off; off >>= 1) {
            p0 += __shfl_xor(p0, off);
            p1 += __shfl_xor(p1, off);
        }
        if (lane == 0) {
            outL[wv * 16 + cc]     = p0;
            outL[wv * 16 + cc + 1] = p1;
        }
    }
    __syncthreads();
    if (tid < 128)
        out[(size_t)b * Cch + cg * 128 + tid] = outL[tid];
}

// ---------------------------------------------------------------------------
extern "C" void kernel_launch(void* const* d_in, const int* in_sizes, int n_in,
                              void* d_out, int out_size, void* d_ws, size_t ws_size,
                              hipStream_t stream) {
    const float* text = (const float*)d_in[0];   // [64, 768]
    const float* img  = (const float*)d_in[1];   // [64, 2048, 19, 19]
    const float* W    = (const float*)d_in[2];   // [2048, 768]
    const float* bias = (const float*)d_in[3];   // [2048]
    float* out = (float*)d_out;                  // [64, 2048]

    // ws: qT (2048*64) + sims_part (64*16*361) + wts (64*361) fp32, cnt (64 i32)
    float* qT        = (float*)d_ws;
    float* sims_part = qT + (size_t)Cch * Bsz;
    float* wts       = sims_part + (size_t)Bsz * 16 * Ssp;
    int*   cnt       = (int*)(wts + (size_t)Bsz * Ssp);

    // ws is poisoned 0xAA before every launch — zero the counters (graph-safe)
    hipMemsetAsync(cnt, 0, Bsz * sizeof(int), stream);

    k_qgemm<<<dim3(256, 8), 256, 0, stream>>>(text, W, bias, qT);
    k_sims <<<dim3(Bsz, 16), 384, 0, stream>>>(img, qT, sims_part, wts, cnt);
    k_pool <<<dim3(Bsz, 16), 512, 0, stream>>>(img, wts, out);
}

// Round 4
// 318.259 us; speedup vs baseline: 1.1617x; 1.1617x over previous
//
#include <hip/hip_runtime.h>
#include <math.h>

#define Bsz  64
#define Cch  2048
#define Kdim 768
#define Ssp  361

// ---------------------------------------------------------------------------
// K1: qT[c][b] = dot(text[b,:], W[c,:]) + bias[c]
// grid = (256, 8) x 256 threads; wave owns 2 channels (W rows in 24 VGPRs),
// 8 batches per wave processed in PAIRS -> 6 float4 loads + 4 independent
// FMA/shuffle chains in flight. 32 waves/CU.
// ---------------------------------------------------------------------------
__global__ __launch_bounds__(256) void k_qgemm(
    const float* __restrict__ text, const float* __restrict__ W,
    const float* __restrict__ bias, float* __restrict__ qT)
{
    const int lane = threadIdx.x & 63;
    const int wv   = threadIdx.x >> 6;
    const int c0   = blockIdx.x * 8 + wv * 2;
    const int b0   = blockIdx.y * 8;

    const float4* wA = (const float4*)(W + (size_t)c0 * Kdim);
    const float4* wB = (const float4*)(W + (size_t)(c0 + 1) * Kdim);
    const float4 a0 = wA[lane*3+0], a1 = wA[lane*3+1], a2 = wA[lane*3+2];
    const float4 g0 = wB[lane*3+0], g1 = wB[lane*3+1], g2 = wB[lane*3+2];
    const float biasA = bias[c0], biasB = bias[c0 + 1];

    for (int b = b0; b < b0 + 8; b += 2) {
        const float4* tp = (const float4*)(text + (size_t)b * Kdim);
        const float4* up = (const float4*)(text + (size_t)(b + 1) * Kdim);
        const float4 t0 = tp[lane*3+0], t1 = tp[lane*3+1], t2 = tp[lane*3+2];
        const float4 u0 = up[lane*3+0], u1 = up[lane*3+1], u2 = up[lane*3+2];

        float r00 = a0.x*t0.x + a0.y*t0.y + a0.z*t0.z + a0.w*t0.w
                  + a1.x*t1.x + a1.y*t1.y + a1.z*t1.z + a1.w*t1.w
                  + a2.x*t2.x + a2.y*t2.y + a2.z*t2.z + a2.w*t2.w;
        float r10 = g0.x*t0.x + g0.y*t0.y + g0.z*t0.z + g0.w*t0.w
                  + g1.x*t1.x + g1.y*t1.y + g1.z*t1.z + g1.w*t1.w
                  + g2.x*t2.x + g2.y*t2.y + g2.z*t2.z + g2.w*t2.w;
        float r01 = a0.x*u0.x + a0.y*u0.y + a0.z*u0.z + a0.w*u0.w
                  + a1.x*u1.x + a1.y*u1.y + a1.z*u1.z + a1.w*u1.w
                  + a2.x*u2.x + a2.y*u2.y + a2.z*u2.z + a2.w*u2.w;
        float r11 = g0.x*u0.x + g0.y*u0.y + g0.z*u0.z + g0.w*u0.w
                  + g1.x*u1.x + g1.y*u1.y + g1.z*u1.z + g1.w*u1.w
                  + g2.x*u2.x + g2.y*u2.y + g2.z*u2.z + g2.w*u2.w;
        #pragma unroll
        for (int off = 32; off; off >>= 1) {
            r00 += __shfl_xor(r00, off);
            r10 += __shfl_xor(r10, off);
            r01 += __shfl_xor(r01, off);
            r11 += __shfl_xor(r11, off);
        }
        if (lane == 0) {
            qT[(size_t)c0 * Bsz + b]           = r00 + biasA;
            qT[(size_t)(c0 + 1) * Bsz + b]     = r10 + biasB;
            qT[(size_t)c0 * Bsz + b + 1]       = r01 + biasA;
            qT[(size_t)(c0 + 1) * Bsz + b + 1] = r11 + biasB;
        }
    }
}

// ---------------------------------------------------------------------------
// K2: partial sims. grid (b=64, cg=16) x 384 threads; thread = spatial s.
// sims_part[b][cg][s] = sum over 128 channels of q[b,c]*img[b,c,s].
// EXPLICIT 16-deep load batching: 16 outstanding 256 B wave-loads ->
// ~98 KB in flight per CU (vs ~9 KB Little's-law need at HBM BW).
// ---------------------------------------------------------------------------
__global__ __launch_bounds__(384) void k_sims(
    const float* __restrict__ img, const float* __restrict__ qT,
    float* __restrict__ sims_part)
{
    const int b  = blockIdx.x;
    const int cg = blockIdx.y;
    const int tid = threadIdx.x;

    __shared__ float qL[128];
    if (tid < 128) qL[tid] = qT[(size_t)(cg * 128 + tid) * Bsz + b];
    __syncthreads();

    if (tid < Ssp) {
        const float* base = img + ((size_t)b * Cch + (size_t)cg * 128) * Ssp + tid;
        float acc = 0.f;
        for (int c0 = 0; c0 < 128; c0 += 16) {
            float v[16];
            #pragma unroll
            for (int j = 0; j < 16; j++)
                v[j] = base[(size_t)(c0 + j) * Ssp];
            #pragma unroll
            for (int j = 0; j < 16; j++)
                acc += qL[c0 + j] * v[j];
        }
        sims_part[((size_t)b * 16 + cg) * Ssp + tid] = acc;
    }
}

// ---------------------------------------------------------------------------
// K3: weights. grid = 64 blocks x 384 threads; thread = spatial s.
// Sums the 16 partials, block softmax, writes PRE-NORMALIZED weights.
// (Separate dispatch — round 3 showed the fused fence/atomic tail costs
// ~30 us, far more than this kernel's launch.)
// ---------------------------------------------------------------------------
__global__ __launch_bounds__(384) void k_wts(
    const float* __restrict__ sims_part, float* __restrict__ wts)
{
    const int b   = blockIdx.x;
    const int tid = threadIdx.x;
    const int lane = tid & 63;
    const int wv   = tid >> 6;

    __shared__ float red[6];

    float s0 = -1e30f;
    if (tid < Ssp) {
        float a = 0.f;
        #pragma unroll
        for (int g = 0; g < 16; g++)
            a += sims_part[((size_t)b * 16 + g) * Ssp + tid];
        s0 = a;
    }

    float m = s0;
    #pragma unroll
    for (int off = 32; off; off >>= 1) m = fmaxf(m, __shfl_xor(m, off));
    if (lane == 0) red[wv] = m;
    __syncthreads();
    m = red[0];
    #pragma unroll
    for (int w = 1; w < 6; w++) m = fmaxf(m, red[w]);
    __syncthreads();

    const float e0 = (tid < Ssp) ? __expf(s0 - m) : 0.f;
    float l = e0;
    #pragma unroll
    for (int off = 32; off; off >>= 1) l += __shfl_xor(l, off);
    if (lane == 0) red[wv] = l;
    __syncthreads();
    l = red[0] + red[1] + red[2] + red[3] + red[4] + red[5];

    if (tid < Ssp)
        wts[(size_t)b * Ssp + tid] = e0 / l;
}

// ---------------------------------------------------------------------------
// K4: weighted pooling. grid (b=64, cg=16) x 256 threads; wave owns 32
// channels processed 4-at-a-time -> 24 outstanding loads, 4 interleaved
// reduce chains. Weights held in 6 registers per lane (read straight from
// global — wts is 92 KB, L2-hot). Coalesced 128-wide store via LDS gather.
// ---------------------------------------------------------------------------
__global__ __launch_bounds__(256) void k_pool(
    const float* __restrict__ img, const float* __restrict__ wts,
    float* __restrict__ out)
{
    const int b   = blockIdx.x;
    const int cg  = blockIdx.y;
    const int tid = threadIdx.x;
    const int lane = tid & 63;
    const int wv   = tid >> 6;

    __shared__ float outL[128];

    // weights for this lane's 6 s-slots, in registers
    const float* wb = wts + (size_t)b * Ssp;
    const float w0 = wb[lane];
    const float w1 = wb[lane + 64];
    const float w2 = wb[lane + 128];
    const float w3 = wb[lane + 192];
    const float w4 = wb[lane + 256];
    const float w5 = (lane + 320 < Ssp) ? wb[lane + 320] : 0.f;

    // wave wv handles channels [cg*128 + wv*32, +32), four at a time
    const int cbase = cg * 128 + wv * 32;
    for (int cc = 0; cc < 32; cc += 4) {
        const float* p0 = img + ((size_t)b * Cch + cbase + cc) * Ssp;
        const float* p1 = p0 + Ssp;
        const float* p2 = p1 + Ssp;
        const float* p3 = p2 + Ssp;
        float r0, r1, r2, r3;
        {
            float v00=p0[lane],     v01=p0[lane+64],  v02=p0[lane+128],
                  v03=p0[lane+192], v04=p0[lane+256];
            float v10=p1[lane],     v11=p1[lane+64],  v12=p1[lane+128],
                  v13=p1[lane+192], v14=p1[lane+256];
            float v20=p2[lane],     v21=p2[lane+64],  v22=p2[lane+128],
                  v23=p2[lane+192], v24=p2[lane+256];
            float v30=p3[lane],     v31=p3[lane+64],  v32=p3[lane+128],
                  v33=p3[lane+192], v34=p3[lane+256];
            float v05 = 0.f, v15 = 0.f, v25 = 0.f, v35 = 0.f;
            if (lane + 320 < Ssp) {
                v05 = p0[lane+320]; v15 = p1[lane+320];
                v25 = p2[lane+320]; v35 = p3[lane+320];
            }
            r0 = v00*w0 + v01*w1 + v02*w2 + v03*w3 + v04*w4 + v05*w5;
            r1 = v10*w0 + v11*w1 + v12*w2 + v13*w3 + v14*w4 + v15*w5;
            r2 = v20*w0 + v21*w1 + v22*w2 + v23*w3 + v24*w4 + v25*w5;
            r3 = v30*w0 + v31*w1 + v32*w2 + v33*w3 + v34*w4 + v35*w5;
        }
        #pragma unroll
        for (int off = 32; off; off >>= 1) {
            r0 += __shfl_xor(r0, off);
            r1 += __shfl_xor(r1, off);
            r2 += __shfl_xor(r2, off);
            r3 += __shfl_xor(r3, off);
        }
        if (lane == 0) {
            outL[wv * 32 + cc]     = r0;
            outL[wv * 32 + cc + 1] = r1;
            outL[wv * 32 + cc + 2] = r2;
            outL[wv * 32 + cc + 3] = r3;
        }
    }
    __syncthreads();
    if (tid < 128)
        out[(size_t)b * Cch + cg * 128 + tid] = outL[tid];
}

// ---------------------------------------------------------------------------
extern "C" void kernel_launch(void* const* d_in, const int* in_sizes, int n_in,
                              void* d_out, int out_size, void* d_ws, size_t ws_size,
                              hipStream_t stream) {
    const float* text = (const float*)d_in[0];   // [64, 768]
    const float* img  = (const float*)d_in[1];   // [64, 2048, 19, 19]
    const float* W    = (const float*)d_in[2];   // [2048, 768]
    const float* bias = (const float*)d_in[3];   // [2048]
    float* out = (float*)d_out;                  // [64, 2048]

    // ws: qT (2048*64) + sims_part (64*16*361) + wts (64*361), all fp32
    float* qT        = (float*)d_ws;
    float* sims_part = qT + (size_t)Cch * Bsz;
    float* wts       = sims_part + (size_t)Bsz * 16 * Ssp;

    k_qgemm<<<dim3(256, 8), 256, 0, stream>>>(text, W, bias, qT);
    k_sims <<<dim3(Bsz, 16), 384, 0, stream>>>(img, qT, sims_part);
    k_wts  <<<dim3(Bsz),     384, 0, stream>>>(sims_part, wts);
    k_pool <<<dim3(Bsz, 16), 256, 0, stream>>>(img, wts, out);
}